// Round 14
// baseline (105.611 us; speedup 1.0000x reference)
//
#include <hip/hip_runtime.h>
#include <hip/hip_bf16.h>

typedef _Float16 f16x8 __attribute__((ext_vector_type(8)));
typedef float f32x4 __attribute__((ext_vector_type(4)));
typedef unsigned long long u64;

#define NSEQ 4096
#define DIMM 1024
#define NQKV 3072

#define BAR() asm volatile("s_barrier" ::: "memory")

__device__ __forceinline__ f32x4 mfma16(f16x8 a, f16x8 b, f32x4 c) {
  return __builtin_amdgcn_mfma_f32_16x16x32_f16(a, b, c, 0, 0, 0);
}

__device__ __forceinline__ void glds16(const void* g, void* l) {
  __builtin_amdgcn_global_load_lds(
      (const __attribute__((address_space(1))) void*)g,
      (__attribute__((address_space(3))) void*)l, 16, 0, 0);
}

// ---------------- fused prep: convert_x + 2 transposes + rank_sort ----------------
__global__ __launch_bounds__(256) void prep_kernel(
    const float* __restrict__ x, _Float16* __restrict__ xh,
    const float* __restrict__ Wqkv, _Float16* __restrict__ wqkvt,
    const float* __restrict__ Wout, _Float16* __restrict__ woutt,
    const float* __restrict__ cc, int* __restrict__ sorted_idx,
    float* __restrict__ csort, int* __restrict__ ranko) {
  __shared__ __align__(16) char plds[16640];
  const int bid = blockIdx.x, t = threadIdx.x;
  if (bid < 2048) {
    const int i = bid * 256 + t;
    const float4 a = ((const float4*)x)[i * 2];
    const float4 b = ((const float4*)x)[i * 2 + 1];
    f16x8 o = {(_Float16)a.x, (_Float16)a.y, (_Float16)a.z, (_Float16)a.w,
               (_Float16)b.x, (_Float16)b.y, (_Float16)b.z, (_Float16)b.w};
    ((f16x8*)xh)[i] = o;
  } else if (bid < 3072) {
    const bool qkv = bid < 2816;
    const int sub = qkv ? bid - 2048 : bid - 2816;
    const float* W = qkv ? Wqkv : Wout;
    _Float16* Wt = qkv ? wqkvt : woutt;
    const int Nn = qkv ? 3072 : 1024;
    const int k0 = (sub & 15) * 64, n0 = (sub >> 4) * 64;
    float (*tile)[65] = (float(*)[65])plds;
    const int tx = t & 63, ty = t >> 6;
    for (int rr = ty; rr < 64; rr += 4)
      tile[rr][tx] = W[(size_t)(k0 + rr) * Nn + n0 + tx];
    __syncthreads();
#pragma unroll
    for (int it = 0; it < 2; ++it) {
      const int idx = it * 256 + t;
      const int row = idx >> 3, seg = idx & 7;
      f16x8 v;
#pragma unroll
      for (int j = 0; j < 8; ++j) v[j] = (_Float16)tile[seg * 8 + j][row];
      *(f16x8*)&Wt[(size_t)(n0 + row) * 1024 + k0 + seg * 8] = v;
    }
  } else {
    float* sc = (float*)plds;
#pragma unroll
    for (int it = 0; it < 4; ++it) {
      const int i = it * 256 + t;
      ((float4*)sc)[i] = ((const float4*)cc)[i];
    }
    __syncthreads();
    const int elem = (bid - 3072) * 32 + (t >> 3);
    const int s = t & 7;
    const unsigned mybits = __float_as_uint(sc[elem]);
    int cnt = 0;
#pragma unroll 8
    for (int m = 0; m < 512; ++m) {
      const int j = s + (m << 3);
      const unsigned bj = __float_as_uint(sc[j]);
      cnt += (bj < mybits || (bj == mybits && j < elem)) ? 1 : 0;
    }
    cnt += __shfl_xor(cnt, 1);
    cnt += __shfl_xor(cnt, 2);
    cnt += __shfl_xor(cnt, 4);
    if (s == 0) {
      sorted_idx[cnt] = elem;
      csort[cnt] = sc[elem];
      ranko[elem] = cnt;
    }
  }
}

// ---------------- standalone mask: 512 blocks x 8 waves, 1 query/wave ----------------
__global__ __launch_bounds__(512) void mask_kernel(
    const float* __restrict__ csort, const int* __restrict__ sorted_idx,
    unsigned* __restrict__ masks) {
  const int tid = threadIdx.x, lane = tid & 63, wid = tid >> 6;
  const int p = blockIdx.x * 8 + wid;
  int W0 = 64 * (p >> 6) - 64;
  W0 = min(max(W0, 0), NSEQ - 192);
  const float cp = csort[p];
  u64 key[4];
#pragma unroll
  for (int r = 0; r < 3; ++r) {
    const int w = r * 64 + lane;
    const float d = fabsf(csort[W0 + w] - cp);
    key[r] = (((u64)__float_as_uint(d)) << 20) |
             (((u64)(unsigned)sorted_idx[W0 + w]) << 8) | (unsigned)w;
  }
  key[3] = ~0ull;
#pragma unroll
  for (int k = 2; k <= 256; k <<= 1) {
#pragma unroll
    for (int j = k >> 1; j > 0; j >>= 1) {
      if (j >= 64) {
        const int rj = j >> 6;
#pragma unroll
        for (int r = 0; r < 4; ++r) {
          const int rp = r ^ rj;
          if (rp > r) {
            const bool up = (((r * 64) & k) == 0);
            const u64 a = key[r], b2 = key[rp];
            const bool sw = (a > b2) == up;
            key[r] = sw ? b2 : a;
            key[rp] = sw ? a : b2;
          }
        }
      } else {
#pragma unroll
        for (int r = 0; r < 4; ++r) {
          const u64 pv = __shfl_xor(key[r], j);
          const bool up = (((r * 64 + lane) & k) == 0);
          const bool lower = ((lane & j) == 0);
          const bool takemin = (lower == up);
          const u64 mn = key[r] < pv ? key[r] : pv;
          const u64 mx = key[r] < pv ? pv : key[r];
          key[r] = takemin ? mn : mx;
        }
      }
    }
  }
  const unsigned w0 = (unsigned)(key[0] & 0xffu);
  const unsigned hi = w0 >> 5, bit = 1u << (w0 & 31u);
  unsigned m0w = hi == 0 ? bit : 0u;
  unsigned m1w = hi == 1 ? bit : 0u;
  unsigned m2w = hi == 2 ? bit : 0u;
  unsigned m3w = hi == 3 ? bit : 0u;
  unsigned m4w = hi == 4 ? bit : 0u;
  unsigned m5w = hi == 5 ? bit : 0u;
#pragma unroll
  for (int s = 1; s < 64; s <<= 1) {
    m0w |= __shfl_xor(m0w, s);
    m1w |= __shfl_xor(m1w, s);
    m2w |= __shfl_xor(m2w, s);
    m3w |= __shfl_xor(m3w, s);
    m4w |= __shfl_xor(m4w, s);
    m5w |= __shfl_xor(m5w, s);
  }
  if (lane < 8) {
    unsigned val = 0u;
    val = lane == 0 ? m0w : val;
    val = lane == 1 ? m1w : val;
    val = lane == 2 ? m2w : val;
    val = lane == 3 ? m3w : val;
    val = lane == 4 ? m4w : val;
    val = lane == 5 ? m5w : val;
    masks[p * 8 + lane] = val;
  }
}

// ================= shared GEMM helpers =================
__device__ __forceinline__ f16x8 ldsfrag(const char* base, int r, int g) {
  return *(const f16x8*)(base + r * 128 + ((g ^ (r & 7)) << 4));
}

__device__ __forceinline__ void stage_half(const char* gbase, size_t kb, int t,
                                           char* lds_half, int tid) {
#pragma unroll
  for (int s = 0; s < 2; ++s) {
    const int rel = tid * 16 + s * 8192;
    const int r = rel >> 7;
    const int g = (rel >> 4) & 7;
    const int gg = g ^ (r & 7);
    glds16(gbase + (size_t)r * kb + t * 128 + gg * 16, lds_half + rel);
  }
}

__device__ __forceinline__ void stage_64r(const char* gbase, size_t kb, int t,
                                          char* lds8k, int tid) {
  const int rel = tid * 16;
  const int r = rel >> 7;
  const int g = (rel >> 4) & 7;
  const int gg = g ^ (r & 7);
  glds16(gbase + (size_t)r * kb + t * 128 + gg * 16, lds8k + rel);
}

__device__ __forceinline__ void rd_b3(const char* Bb, int wn, int lr, int kg,
                                      f16x8 (&bf)[3][2]) {
#pragma unroll
  for (int nt = 0; nt < 3; ++nt) {
    bf[nt][0] = ldsfrag(Bb, wn + nt * 16 + lr, kg);
    bf[nt][1] = ldsfrag(Bb, wn + nt * 16 + lr, 4 + kg);
  }
}

template <int Q>
__device__ __forceinline__ void rd_a(const char* Ab, int wm, int lr, int kg,
                                     f16x8 (&af)[2][2]) {
#pragma unroll
  for (int m = 0; m < 2; ++m) {
    af[m][0] = ldsfrag(Ab, wm + (2 * Q + m) * 16 + lr, kg);
    af[m][1] = ldsfrag(Ab, wm + (2 * Q + m) * 16 + lr, 4 + kg);
  }
}

// ================= 128x192 4-phase QKV GEMM (grid 512 = 2 blocks/CU) =================
template <int Q>
__device__ __forceinline__ void do_mfma2(const f16x8 (&af)[2][2],
                                         const f16x8 (&bf)[3][2],
                                         f32x4 (&acc)[4][3]) {
#pragma unroll
  for (int m = 0; m < 2; ++m)
#pragma unroll
    for (int nt = 0; nt < 3; ++nt) {
      acc[2 * Q + m][nt] = mfma16(af[m][0], bf[nt][0], acc[2 * Q + m][nt]);
      acc[2 * Q + m][nt] = mfma16(af[m][1], bf[nt][1], acc[2 * Q + m][nt]);
    }
}

// LDS: A0 @0 (16K), A1 @16K, B0 @32K (24K), B1 @56K (24K) = 80KB
// pair = tiles (even->A0/B0, odd->A1/B1); t1 = odd tile, t2/t3 = next even/odd.
// Ledger (loads/thread): stage_half=2, stage_64r=1.
//  p0: rd B0+A0(m01); stage A(t1)->A1[2]
//  p1: rd A0(m23);    stage B(t2)u01->B0[2];  vmcnt(2) (retire A(t1); keep B(t2)u01... wait:
//      outstanding = A(t1)2 + B(t2)2 = 4; need A(t1) done -> keep newest 2 -> vmcnt(2))
//  p2: rd B1+A1(m01); stage B(t2)u2->B0[1], A(t2)->A0[2]
//  p3: rd A1(m23);    stage B(t3)u012->B1[3]; vmcnt(3) (retire B(t2)+A(t2); keep B(t3))
template <bool LAST>
__device__ __forceinline__ void ktile_pair128(const char* Ag, const char* Bg,
                                              size_t kb, char* smem, int tid,
                                              int wm, int wn, int lr, int kg,
                                              int t1, int t2, int t3,
                                              f32x4 (&acc)[4][3]) {
  char* A0 = smem;
  char* A1 = smem + 16384;
  char* B0 = smem + 32768;
  char* B1 = smem + 57344;
  f16x8 bf[3][2], af[2][2];
  // p0
  rd_b3(B0, wn, lr, kg, bf);
  rd_a<0>(A0, wm, lr, kg, af);
  stage_half(Ag, kb, t1, A1, tid);
  BAR();
  __builtin_amdgcn_s_setprio(1);
  do_mfma2<0>(af, bf, acc);
  __builtin_amdgcn_s_setprio(0);
  BAR();
  // p1
  rd_a<1>(A0, wm, lr, kg, af);
  if (!LAST) {
    stage_64r(Bg, kb, t2, B0, tid);
    stage_64r(Bg + 64 * kb, kb, t2, B0 + 8192, tid);
  }
  BAR();
  __builtin_amdgcn_s_setprio(1);
  do_mfma2<1>(af, bf, acc);
  __builtin_amdgcn_s_setprio(0);
  if (LAST)
    asm volatile("s_waitcnt vmcnt(0)" ::: "memory");
  else
    asm volatile("s_waitcnt vmcnt(2)" ::: "memory");
  BAR();
  // p2
  rd_b3(B1, wn, lr, kg, bf);
  rd_a<0>(A1, wm, lr, kg, af);
  if (!LAST) {
    stage_64r(Bg + 128 * kb, kb, t2, B0 + 16384, tid);
    stage_half(Ag, kb, t2, A0, tid);
  }
  BAR();
  __builtin_amdgcn_s_setprio(1);
  do_mfma2<0>(af, bf, acc);
  __builtin_amdgcn_s_setprio(0);
  BAR();
  // p3
  rd_a<1>(A1, wm, lr, kg, af);
  if (!LAST) {
    stage_64r(Bg, kb, t3, B1, tid);
    stage_64r(Bg + 64 * kb, kb, t3, B1 + 8192, tid);
    stage_64r(Bg + 128 * kb, kb, t3, B1 + 16384, tid);
  }
  BAR();
  __builtin_amdgcn_s_setprio(1);
  do_mfma2<1>(af, bf, acc);
  __builtin_amdgcn_s_setprio(0);
  if (!LAST) asm volatile("s_waitcnt vmcnt(3)" ::: "memory");
  BAR();
}

// C rows written in SORTED order via ranko.
__global__ __launch_bounds__(512, 4) void qkv_gemm128_kernel(
    const _Float16* __restrict__ A, const _Float16* __restrict__ Bt,
    const float* __restrict__ bias, const int* __restrict__ ranko,
    _Float16* __restrict__ C) {
  extern __shared__ char smem[];
  const int NN = 3072;
  const size_t kb = 2048;
  const int tid = threadIdx.x;
  const int lane = tid & 63, wid = tid >> 6;
  const int lr = lane & 15, kg = lane >> 4;
  const int wm = (wid >> 2) * 64, wn = (wid & 3) * 48;
  // 512 blocks: XCD r gets 8bx x 8by region (bijective)
  const int r8 = blockIdx.x & 7, idx = blockIdx.x >> 3;
  const int bx = (r8 & 3) * 8 + (idx >> 3);   // 0..31
  const int by = (r8 >> 2) * 8 + (idx & 7);   // 0..15
  const int m0 = bx * 128, n0 = by * 192;
  const char* Ag = (const char*)A + (size_t)m0 * kb;
  const char* Bg = (const char*)Bt + (size_t)n0 * kb;
  char* A0 = smem;
  char* B0 = smem + 32768;
  char* B1 = smem + 57344;
  f32x4 acc[4][3] = {};
  // prologue: A(t0)->A0 [2], B(t0)->B0 [3], B(t1)->B1 [3]; keep newest 3
  stage_half(Ag, kb, 0, A0, tid);
#pragma unroll
  for (int u = 0; u < 3; ++u)
    stage_64r(Bg + (size_t)(64 * u) * kb, kb, 0, B0 + u * 8192, tid);
#pragma unroll
  for (int u = 0; u < 3; ++u)
    stage_64r(Bg + (size_t)(64 * u) * kb, kb, 1, B1 + u * 8192, tid);
  asm volatile("s_waitcnt vmcnt(3)" ::: "memory");
  BAR();
#pragma unroll 1
  for (int i = 0; i < 7; ++i)
    ktile_pair128<false>(Ag, Bg, kb, smem, tid, wm, wn, lr, kg, 2 * i + 1,
                         2 * i + 2, 2 * i + 3, acc);
  ktile_pair128<true>(Ag, Bg, kb, smem, tid, wm, wn, lr, kg, 15, 16, 17, acc);
#pragma unroll
  for (int mt = 0; mt < 4; ++mt) {
    const int row0 = m0 + wm + mt * 16 + kg * 4;
    int srow[4];
#pragma unroll
    for (int rr = 0; rr < 4; ++rr) srow[rr] = ranko[row0 + rr];
#pragma unroll
    for (int nt = 0; nt < 3; ++nt) {
      const int col = n0 + wn + nt * 16 + lr;
      const float bv = bias[col];
#pragma unroll
      for (int rr = 0; rr < 4; ++rr)
        C[(size_t)srow[rr] * NN + col] = (_Float16)(acc[mt][nt][rr] + bv);
    }
  }
}

// ================= 128x128 triple-buffered OUT GEMM (grid 256 = 32x8) =================
__global__ __launch_bounds__(512, 2) void out_gemm128_kernel(
    const _Float16* __restrict__ A, const _Float16* __restrict__ Bt,
    const float* __restrict__ bias, float* __restrict__ C) {
  extern __shared__ char smem[];
  const size_t kb = 2048;
  const int tid = threadIdx.x;
  const int lane = tid & 63, wid = tid >> 6;
  const int lr = lane & 15, kg = lane >> 4;
  const int wm = (wid >> 2) * 64, wn = (wid & 3) * 32;
  const int r8 = blockIdx.x & 7, idx = blockIdx.x >> 3;
  const int bx = (r8 & 3) * 8 + (idx >> 2);
  const int by = (r8 >> 2) * 4 + (idx & 3);
  const int m0 = bx * 128, n0 = by * 128;
  const char* Ag = (const char*)A + (size_t)m0 * kb;
  const char* Bg = (const char*)Bt + (size_t)n0 * kb;
  f32x4 acc[4][2] = {};
  stage_half(Ag, kb, 0, smem, tid);
  stage_half(Bg, kb, 0, smem + 49152, tid);
  stage_half(Ag, kb, 1, smem + 16384, tid);
  stage_half(Bg, kb, 1, smem + 49152 + 16384, tid);
  asm volatile("s_waitcnt vmcnt(4)" ::: "memory");
  BAR();
#pragma unroll
  for (int t = 0; t < 16; ++t) {
    const char* At = smem + (t % 3) * 16384;
    const char* Bb = smem + 49152 + (t % 3) * 16384;
    f16x8 bf[2][2], af[4][2];
#pragma unroll
    for (int nt = 0; nt < 2; ++nt) {
      bf[nt][0] = ldsfrag(Bb, wn + nt * 16 + lr, kg);
      bf[nt][1] = ldsfrag(Bb, wn + nt * 16 + lr, 4 + kg);
    }
#pragma unroll
    for (int m = 0; m < 4; ++m) {
      af[m][0] = ldsfrag(At, wm + m * 16 + lr, kg);
      af[m][1] = ldsfrag(At, wm + m * 16 + lr, 4 + kg);
    }
    if (t < 14) {
      stage_half(Ag, kb, t + 2, smem + ((t + 2) % 3) * 16384, tid);
      stage_half(Bg, kb, t + 2, smem + 49152 + ((t + 2) % 3) * 16384, tid);
    }
    BAR();
    __builtin_amdgcn_s_setprio(1);
#pragma unroll
    for (int m = 0; m < 4; ++m)
#pragma unroll
      for (int nt = 0; nt < 2; ++nt) {
        acc[m][nt] = mfma16(af[m][0], bf[nt][0], acc[m][nt]);
        acc[m][nt] = mfma16(af[m][1], bf[nt][1], acc[m][nt]);
      }
    __builtin_amdgcn_s_setprio(0);
    if (t < 14)
      asm volatile("s_waitcnt vmcnt(4)" ::: "memory");
    else if (t == 14)
      asm volatile("s_waitcnt vmcnt(0)" ::: "memory");
    BAR();
  }
#pragma unroll
  for (int nt = 0; nt < 2; ++nt) {
    const int col = n0 + wn + nt * 16 + lr;
    const float bv = bias[col];
#pragma unroll
    for (int mt = 0; mt < 4; ++mt) {
      const int row0 = m0 + wm + mt * 16 + kg * 4;
#pragma unroll
      for (int rr = 0; rr < 4; ++rr)
        C[(size_t)(row0 + rr) * 1024 + col] = acc[mt][nt][rr] + bv;
    }
  }
}

// ---------------- fused windowed attention, 192-window, sorted qkvs ----------------
__global__ __launch_bounds__(256) void attn_kernel(
    const _Float16* __restrict__ qkvs, const unsigned* __restrict__ masks,
    const int* __restrict__ sorted_idx, _Float16* __restrict__ attn_h) {
  __shared__ __align__(128) char sK[24576];  // K [192][128B]; later P [64][384B]
  __shared__ __align__(128) char sV[24576];  // V^T [64][384B] (swizzled)
  const int flat = (blockIdx.x & 7) * 128 + (blockIdx.x >> 3);
  const int b = flat & 63, h = flat >> 6;
  const int tid = threadIdx.x, lane = tid & 63, wid = tid >> 6;
  const int W0 = min(max(64 * b - 64, 0), NSEQ - 192);
  const int lrow16 = lane & 15, kgrp = lane >> 4;
#pragma unroll
  for (int c = 0; c < 6; ++c) {
    const int o = c * 4096 + wid * 1024 + lane * 16;
    const int row = o >> 7;
    const int inrow = (o & 127) ^ ((row & 7) << 4);
    glds16((const char*)qkvs + (size_t)(W0 + row) * 6144 + 2048 + h * 128 + inrow,
           sK + o);
  }
  f16x8 vreg[6];
#pragma unroll
  for (int c = 0; c < 6; ++c) {
    const int o = c * 4096 + wid * 1024 + lane * 16;
    vreg[c] = *(const f16x8*)((const char*)qkvs + (size_t)(W0 + (o >> 7)) * 6144 +
                              4096 + h * 128 + (o & 127));
  }
  const int p_base = b * 64 + wid * 16;
  const char* qp =
      (const char*)qkvs + (size_t)(p_base + lrow16) * 6144 + h * 128 + kgrp * 16;
  const f16x8 aq0 = *(const f16x8*)qp;
  const f16x8 aq1 = *(const f16x8*)(qp + 64);
  unsigned mb[4];
#pragma unroll
  for (int r = 0; r < 4; ++r) {
    const int p = p_base + kgrp * 4 + r;
    const uint4 wa = *(const uint4*)&masks[p * 8];
    const uint2 wb2 = *(const uint2*)&masks[p * 8 + 4];
    const unsigned wsv6[6] = {wa.x, wa.y, wa.z, wa.w, wb2.x, wb2.y};
    unsigned bits = 0;
#pragma unroll
    for (int n = 0; n < 12; ++n)
      bits |= ((wsv6[n >> 1] >> (((n & 1) << 4) + lrow16)) & 1u) << n;
    mb[r] = bits;
  }
  const int lrot = lane & 7;
#pragma unroll
  for (int c = 0; c < 6; ++c) {
    const int o = c * 4096 + wid * 1024 + lane * 16;
    const int k = o >> 7;
    const int d0 = (o & 127) >> 1;
#pragma unroll
    for (int ee = 0; ee < 8; ++ee) {
      const int e = (ee + lrot) & 7;
      const int d = d0 + e;
      *(_Float16*)(sV + d * 384 + ((2 * k) ^ ((d & 7) << 4))) = vreg[c][e];
    }
  }
  __syncthreads();
  float sv[12][4];
#pragma unroll
  for (int n = 0; n < 12; ++n) {
    const int j = n * 16 + lrow16;
    const int sw = (j & 7) << 4;
    const char* kr = sK + j * 128;
    const f16x8 b0 = *(const f16x8*)(kr + ((kgrp * 16) ^ sw));
    const f16x8 b1 = *(const f16x8*)(kr + ((64 + kgrp * 16) ^ sw));
    f32x4 a = {};
    a = mfma16(aq0, b0, a);
    a = mfma16(aq1, b1, a);
#pragma unroll
    for (int r = 0; r < 4; ++r)
      sv[n][r] = ((mb[r] >> n) & 1u) ? a[r] * 0.125f : -1e30f;
  }
#pragma unroll
  for (int r = 0; r < 4; ++r) {
    float m = sv[0][r];
#pragma unroll
    for (int n = 1; n < 12; ++n) m = fmaxf(m, sv[n][r]);
    m = fmaxf(m, __shfl_xor(m, 1));
    m = fmaxf(m, __shfl_xor(m, 2));
    m = fmaxf(m, __shfl_xor(m, 4));
    m = fmaxf(m, __shfl_xor(m, 8));
    float s = 0.f;
#pragma unroll
    for (int n = 0; n < 12; ++n) {
      const float e = __expf(sv[n][r] - m);
      sv[n][r] = e;
      s += e;
    }
    s += __shfl_xor(s, 1);
    s += __shfl_xor(s, 2);
    s += __shfl_xor(s, 4);
    s += __shfl_xor(s, 8);
    const float rinv = 1.f / s;
#pragma unroll
    for (int n = 0; n < 12; ++n) sv[n][r] *= rinv;
  }
  __syncthreads();
#pragma unroll
  for (int n = 0; n < 12; ++n) {
#pragma unroll
    for (int r = 0; r < 4; ++r) {
      const int lrw = wid * 16 + kgrp * 4 + r;
      const int cb = (n * 16 + lrow16) * 2;
      *(_Float16*)(sK + lrw * 384 + (cb ^ ((lrw & 7) << 4))) = (_Float16)sv[n][r];
    }
  }
  __syncthreads();
  f32x4 oacc[4] = {};
  const int arow = wid * 16 + lrow16;
  const int swa = (arow & 7) << 4;
#pragma unroll
  for (int kt = 0; kt < 6; ++kt) {
    const int kbo = kt * 64 + kgrp * 16;
    const f16x8 pa = *(const f16x8*)(sK + arow * 384 + (kbo ^ swa));
#pragma unroll
    for (int nt = 0; nt < 4; ++nt) {
      const int d = nt * 16 + lrow16;
      const f16x8 vb = *(const f16x8*)(sV + d * 384 + (kbo ^ ((d & 7) << 4)));
      oacc[nt] = mfma16(pa, vb, oacc[nt]);
    }
  }
#pragma unroll
  for (int r = 0; r < 4; ++r) {
    const int p = p_base + kgrp * 4 + r;
    const int orig = sorted_idx[p];
    _Float16* op = attn_h + (size_t)orig * DIMM + h * 64;
#pragma unroll
    for (int nt = 0; nt < 4; ++nt)
      op[nt * 16 + lrow16] = (_Float16)oacc[nt][r];
  }
}

// ---------------- launch ----------------
extern "C" void kernel_launch(void* const* d_in, const int* in_sizes, int n_in,
                              void* d_out, int out_size, void* d_ws, size_t ws_size,
                              hipStream_t stream) {
  const float* x = (const float*)d_in[0];
  const float* cc = (const float*)d_in[1];
  const float* Wqkv = (const float*)d_in[2];
  const float* bqkv = (const float*)d_in[3];
  const float* Wout = (const float*)d_in[4];
  const float* bout = (const float*)d_in[5];
  char* ws = (char*)d_ws;

  _Float16* xh = (_Float16*)(ws + 0);                 //  8 MB
  _Float16* wqkvt = (_Float16*)(ws + 8388608);        //  6 MB
  _Float16* woutt = (_Float16*)(ws + 14680064);       //  2 MB
  _Float16* qkvs = (_Float16*)(ws + 16777216);        // 24 MB (sorted rows)
  _Float16* atnh = (_Float16*)(ws + 41943040);        //  8 MB
  int* sidx = (int*)(ws + 50331648);                  // 16 KB
  float* csort = (float*)(ws + 50348032);             // 16 KB
  int* rankb = (int*)(ws + 50364416);                 // 16 KB
  unsigned* msk = (unsigned*)(ws + 50380800);         // 128 KB

  hipFuncSetAttribute((const void*)qkv_gemm128_kernel,
                      hipFuncAttributeMaxDynamicSharedMemorySize, 81920);
  hipFuncSetAttribute((const void*)out_gemm128_kernel,
                      hipFuncAttributeMaxDynamicSharedMemorySize, 98304);

  prep_kernel<<<3200, 256, 0, stream>>>(x, xh, Wqkv, wqkvt, Wout, woutt, cc,
                                        sidx, csort, rankb);
  mask_kernel<<<512, 512, 0, stream>>>(csort, sidx, msk);
  qkv_gemm128_kernel<<<512, 512, 81920, stream>>>(xh, wqkvt, bqkv, rankb,
                                                  qkvs);
  attn_kernel<<<1024, 256, 0, stream>>>(qkvs, msk, sidx, atnh);
  out_gemm128_kernel<<<256, 512, 98304, stream>>>(atnh, woutt, bout,
                                                  (float*)d_out);
}

// Round 15
// 101.895 us; speedup vs baseline: 1.0365x; 1.0365x over previous
//
#include <hip/hip_runtime.h>
#include <hip/hip_bf16.h>

typedef _Float16 f16x8 __attribute__((ext_vector_type(8)));
typedef float f32x4 __attribute__((ext_vector_type(4)));
typedef unsigned long long u64;

#define NSEQ 4096
#define DIMM 1024
#define NQKV 3072

#define BAR() asm volatile("s_barrier" ::: "memory")

__device__ __forceinline__ f32x4 mfma16(f16x8 a, f16x8 b, f32x4 c) {
  return __builtin_amdgcn_mfma_f32_16x16x32_f16(a, b, c, 0, 0, 0);
}

__device__ __forceinline__ void glds16(const void* g, void* l) {
  __builtin_amdgcn_global_load_lds(
      (const __attribute__((address_space(1))) void*)g,
      (__attribute__((address_space(3))) void*)l, 16, 0, 0);
}

// ---------------- fused prep: convert_x + 2 transposes + rank_sort ----------------
__global__ __launch_bounds__(256) void prep_kernel(
    const float* __restrict__ x, _Float16* __restrict__ xh,
    const float* __restrict__ Wqkv, _Float16* __restrict__ wqkvt,
    const float* __restrict__ Wout, _Float16* __restrict__ woutt,
    const float* __restrict__ cc, int* __restrict__ sorted_idx,
    float* __restrict__ csort) {
  __shared__ __align__(16) char plds[16640];
  const int bid = blockIdx.x, t = threadIdx.x;
  if (bid < 2048) {
    const int i = bid * 256 + t;
    const float4 a = ((const float4*)x)[i * 2];
    const float4 b = ((const float4*)x)[i * 2 + 1];
    f16x8 o = {(_Float16)a.x, (_Float16)a.y, (_Float16)a.z, (_Float16)a.w,
               (_Float16)b.x, (_Float16)b.y, (_Float16)b.z, (_Float16)b.w};
    ((f16x8*)xh)[i] = o;
  } else if (bid < 3072) {
    const bool qkv = bid < 2816;
    const int sub = qkv ? bid - 2048 : bid - 2816;
    const float* W = qkv ? Wqkv : Wout;
    _Float16* Wt = qkv ? wqkvt : woutt;
    const int Nn = qkv ? 3072 : 1024;
    const int k0 = (sub & 15) * 64, n0 = (sub >> 4) * 64;
    float (*tile)[65] = (float(*)[65])plds;
    const int tx = t & 63, ty = t >> 6;
    for (int rr = ty; rr < 64; rr += 4)
      tile[rr][tx] = W[(size_t)(k0 + rr) * Nn + n0 + tx];
    __syncthreads();
    for (int ccn = ty; ccn < 64; ccn += 4)
      Wt[(size_t)(n0 + ccn) * 1024 + k0 + tx] = (_Float16)tile[tx][ccn];
  } else {
    float* sc = (float*)plds;
#pragma unroll
    for (int it = 0; it < 4; ++it) {
      const int i = it * 256 + t;
      ((float4*)sc)[i] = ((const float4*)cc)[i];
    }
    __syncthreads();
    const int elem = (bid - 3072) * 32 + (t >> 3);
    const int s = t & 7;
    const unsigned mybits = __float_as_uint(sc[elem]);
    int cnt = 0;
#pragma unroll 8
    for (int m = 0; m < 512; ++m) {
      const int j = s + (m << 3);
      const unsigned bj = __float_as_uint(sc[j]);
      cnt += (bj < mybits || (bj == mybits && j < elem)) ? 1 : 0;
    }
    cnt += __shfl_xor(cnt, 1);
    cnt += __shfl_xor(cnt, 2);
    cnt += __shfl_xor(cnt, 4);
    if (s == 0) {
      sorted_idx[cnt] = elem;
      csort[cnt] = sc[elem];
    }
  }
}

// ---------------- per-query exact top-64 within 192-window -> mask ----------------
__global__ __launch_bounds__(256) void mask_kernel(
    const float* __restrict__ csort, const int* __restrict__ sorted_idx,
    unsigned* __restrict__ masks) {
  __shared__ unsigned lm[4][8];
  const int tid = threadIdx.x, lane = tid & 63, wid = tid >> 6;
  const int p = blockIdx.x * 4 + wid;
  int W0 = 64 * (p >> 6) - 64;
  W0 = min(max(W0, 0), NSEQ - 192);
  const float cp = csort[p];
  u64 key[4];
#pragma unroll
  for (int r = 0; r < 3; ++r) {
    const int w = r * 64 + lane;
    const float d = fabsf(csort[W0 + w] - cp);
    key[r] = (((u64)__float_as_uint(d)) << 20) |
             (((u64)(unsigned)sorted_idx[W0 + w]) << 8) | (unsigned)w;
  }
  key[3] = ~0ull;
  if (lane < 8) lm[wid][lane] = 0u;
#pragma unroll
  for (int k = 2; k <= 256; k <<= 1) {
#pragma unroll
    for (int j = k >> 1; j > 0; j >>= 1) {
      if (j >= 64) {
        const int rj = j >> 6;
#pragma unroll
        for (int r = 0; r < 4; ++r) {
          const int rp = r ^ rj;
          if (rp > r) {
            const bool up = (((r * 64) & k) == 0);
            const u64 a = key[r], b2 = key[rp];
            const bool sw = (a > b2) == up;
            key[r] = sw ? b2 : a;
            key[rp] = sw ? a : b2;
          }
        }
      } else {
#pragma unroll
        for (int r = 0; r < 4; ++r) {
          const u64 pv = __shfl_xor(key[r], j);
          const bool up = (((r * 64 + lane) & k) == 0);
          const bool lower = ((lane & j) == 0);
          const bool takemin = (lower == up);
          const u64 mn = key[r] < pv ? key[r] : pv;
          const u64 mx = key[r] < pv ? pv : key[r];
          key[r] = takemin ? mn : mx;
        }
      }
    }
  }
  const unsigned w0 = (unsigned)(key[0] & 0xffu);
  atomicOr(&lm[wid][w0 >> 5], 1u << (w0 & 31u));
  __syncthreads();
  if (lane < 8) masks[p * 8 + lane] = lm[wid][lane];
}

// ================= shared GEMM helpers =================
__device__ __forceinline__ f16x8 ldsfrag(const char* base, int r, int g) {
  return *(const f16x8*)(base + r * 128 + ((g ^ (r & 7)) << 4));
}

__device__ __forceinline__ void stage_half(const char* gbase, size_t kb, int t,
                                           char* lds_half, int tid) {
#pragma unroll
  for (int s = 0; s < 2; ++s) {
    const int rel = tid * 16 + s * 8192;
    const int r = rel >> 7;
    const int g = (rel >> 4) & 7;
    const int gg = g ^ (r & 7);
    glds16(gbase + (size_t)r * kb + t * 128 + gg * 16, lds_half + rel);
  }
}

__device__ __forceinline__ void stage_64r(const char* gbase, size_t kb, int t,
                                          char* lds8k, int tid) {
  const int rel = tid * 16;
  const int r = rel >> 7;
  const int g = (rel >> 4) & 7;
  const int gg = g ^ (r & 7);
  glds16(gbase + (size_t)r * kb + t * 128 + gg * 16, lds8k + rel);
}

// ================= 256x192 8-phase QKV GEMM (grid 256 = 16x16) =================
__device__ __forceinline__ void rd_b3(const char* Bb, int wn, int lr, int kg,
                                      f16x8 (&bf)[3][2]) {
#pragma unroll
  for (int nt = 0; nt < 3; ++nt) {
    bf[nt][0] = ldsfrag(Bb, wn + nt * 16 + lr, kg);
    bf[nt][1] = ldsfrag(Bb, wn + nt * 16 + lr, 4 + kg);
  }
}

template <int Q>
__device__ __forceinline__ void rd_a(const char* Ab, int wm, int lr, int kg,
                                     f16x8 (&af)[2][2]) {
#pragma unroll
  for (int m = 0; m < 2; ++m) {
    af[m][0] = ldsfrag(Ab, wm + (2 * Q + m) * 16 + lr, kg);
    af[m][1] = ldsfrag(Ab, wm + (2 * Q + m) * 16 + lr, 4 + kg);
  }
}

template <int Q>
__device__ __forceinline__ void do_mfma3(const f16x8 (&af)[2][2],
                                         const f16x8 (&bf)[3][2],
                                         f32x4 (&acc)[8][3]) {
#pragma unroll
  for (int m = 0; m < 2; ++m)
#pragma unroll
    for (int nt = 0; nt < 3; ++nt) {
      acc[2 * Q + m][nt] = mfma16(af[m][0], bf[nt][0], acc[2 * Q + m][nt]);
      acc[2 * Q + m][nt] = mfma16(af[m][1], bf[nt][1], acc[2 * Q + m][nt]);
    }
}

template <bool LAST>
__device__ __forceinline__ void ktile_pair192(const char* Ag, const char* Bg,
                                              size_t kb, char* smem, int tid,
                                              int wm, int wn, int lr, int kg,
                                              int t1, int t2, int t3,
                                              f32x4 (&acc)[8][3]) {
  char* A0 = smem;
  char* A1 = smem + 32768;
  char* B0 = smem + 65536;
  char* B1 = smem + 65536 + 24576;
  f16x8 bf[3][2], af[2][2];
  rd_b3(B0, wn, lr, kg, bf);
  rd_a<0>(A0, wm, lr, kg, af);
  stage_64r(Ag, kb, t1, A1, tid);
  stage_64r(Ag + 64 * kb, kb, t1, A1 + 8192, tid);
  BAR();
  __builtin_amdgcn_s_setprio(1);
  do_mfma3<0>(af, bf, acc);
  __builtin_amdgcn_s_setprio(0);
  BAR();
  rd_a<1>(A0, wm, lr, kg, af);
  stage_64r(Ag + 128 * kb, kb, t1, A1 + 16384, tid);
  stage_64r(Ag + 192 * kb, kb, t1, A1 + 24576, tid);
  BAR();
  __builtin_amdgcn_s_setprio(1);
  do_mfma3<1>(af, bf, acc);
  __builtin_amdgcn_s_setprio(0);
  BAR();
  rd_a<2>(A0, wm, lr, kg, af);
  if (!LAST) {
    stage_64r(Bg, kb, t2, B0, tid);
    stage_64r(Bg + 64 * kb, kb, t2, B0 + 8192, tid);
  }
  BAR();
  __builtin_amdgcn_s_setprio(1);
  do_mfma3<2>(af, bf, acc);
  __builtin_amdgcn_s_setprio(0);
  BAR();
  rd_a<3>(A0, wm, lr, kg, af);
  if (!LAST) stage_64r(Bg + 128 * kb, kb, t2, B0 + 16384, tid);
  BAR();
  __builtin_amdgcn_s_setprio(1);
  do_mfma3<3>(af, bf, acc);
  __builtin_amdgcn_s_setprio(0);
  if (LAST)
    asm volatile("s_waitcnt vmcnt(0)" ::: "memory");
  else
    asm volatile("s_waitcnt vmcnt(3)" ::: "memory");
  BAR();
  rd_b3(B1, wn, lr, kg, bf);
  rd_a<0>(A1, wm, lr, kg, af);
  if (!LAST) {
    stage_64r(Ag, kb, t2, A0, tid);
    stage_64r(Ag + 64 * kb, kb, t2, A0 + 8192, tid);
  }
  BAR();
  __builtin_amdgcn_s_setprio(1);
  do_mfma3<0>(af, bf, acc);
  __builtin_amdgcn_s_setprio(0);
  BAR();
  rd_a<1>(A1, wm, lr, kg, af);
  if (!LAST) {
    stage_64r(Ag + 128 * kb, kb, t2, A0 + 16384, tid);
    stage_64r(Ag + 192 * kb, kb, t2, A0 + 24576, tid);
  }
  BAR();
  __builtin_amdgcn_s_setprio(1);
  do_mfma3<1>(af, bf, acc);
  __builtin_amdgcn_s_setprio(0);
  BAR();
  rd_a<2>(A1, wm, lr, kg, af);
  if (!LAST) {
    stage_64r(Bg, kb, t3, B1, tid);
    stage_64r(Bg + 64 * kb, kb, t3, B1 + 8192, tid);
  }
  BAR();
  __builtin_amdgcn_s_setprio(1);
  do_mfma3<2>(af, bf, acc);
  __builtin_amdgcn_s_setprio(0);
  BAR();
  rd_a<3>(A1, wm, lr, kg, af);
  if (!LAST) stage_64r(Bg + 128 * kb, kb, t3, B1 + 16384, tid);
  BAR();
  __builtin_amdgcn_s_setprio(1);
  do_mfma3<3>(af, bf, acc);
  __builtin_amdgcn_s_setprio(0);
  if (!LAST) asm volatile("s_waitcnt vmcnt(3)" ::: "memory");
  BAR();
}

__global__ __launch_bounds__(512, 2) void qkv_gemm192_kernel(
    const _Float16* __restrict__ A, const _Float16* __restrict__ Bt,
    const float* __restrict__ bias, _Float16* __restrict__ C) {
  extern __shared__ char smem[];
  const int NN = 3072;
  const size_t kb = 2048;
  const int tid = threadIdx.x;
  const int lane = tid & 63, wid = tid >> 6;
  const int lr = lane & 15, kg = lane >> 4;
  const int wm = (wid >> 2) * 128, wn = (wid & 3) * 48;
  const int bid = blockIdx.x;
  const int flat = (bid & 7) * 32 + (bid >> 3);
  const int bx = flat >> 4, by = flat & 15;
  const int m0 = bx * 256, n0 = by * 192;
  const char* Ag = (const char*)A + (size_t)m0 * kb;
  const char* Bg = (const char*)Bt + (size_t)n0 * kb;
  char* A0 = smem;
  char* B0 = smem + 65536;
  char* B1 = smem + 65536 + 24576;
  f32x4 acc[8][3] = {};
#pragma unroll
  for (int u = 0; u < 4; ++u)
    stage_64r(Ag + (size_t)(64 * u) * kb, kb, 0, A0 + u * 8192, tid);
#pragma unroll
  for (int u = 0; u < 3; ++u)
    stage_64r(Bg + (size_t)(64 * u) * kb, kb, 0, B0 + u * 8192, tid);
#pragma unroll
  for (int u = 0; u < 3; ++u)
    stage_64r(Bg + (size_t)(64 * u) * kb, kb, 1, B1 + u * 8192, tid);
  asm volatile("s_waitcnt vmcnt(3)" ::: "memory");
  BAR();
#pragma unroll 1
  for (int i = 0; i < 7; ++i)
    ktile_pair192<false>(Ag, Bg, kb, smem, tid, wm, wn, lr, kg, 2 * i + 1,
                         2 * i + 2, 2 * i + 3, acc);
  ktile_pair192<true>(Ag, Bg, kb, smem, tid, wm, wn, lr, kg, 15, 16, 17, acc);
#pragma unroll
  for (int nt = 0; nt < 3; ++nt) {
    const int col = n0 + wn + nt * 16 + lr;
    const float bv = bias[col];
#pragma unroll
    for (int mt = 0; mt < 8; ++mt) {
      const int row0 = m0 + wm + mt * 16 + kg * 4;
#pragma unroll
      for (int rr = 0; rr < 4; ++rr)
        C[(size_t)(row0 + rr) * NN + col] = (_Float16)(acc[mt][nt][rr] + bv);
    }
  }
}

// ================= 128x128 triple-buffered OUT GEMM (grid 256 = 32x8) =================
__global__ __launch_bounds__(512, 2) void out_gemm128_kernel(
    const _Float16* __restrict__ A, const _Float16* __restrict__ Bt,
    const float* __restrict__ bias, float* __restrict__ C) {
  extern __shared__ char smem[];
  const size_t kb = 2048;
  const int tid = threadIdx.x;
  const int lane = tid & 63, wid = tid >> 6;
  const int lr = lane & 15, kg = lane >> 4;
  const int wm = (wid >> 2) * 64, wn = (wid & 3) * 32;
  const int bid = blockIdx.x;
  const int flat = (bid & 7) * 32 + (bid >> 3);
  const int bx = flat >> 3, by = flat & 7;
  const int m0 = bx * 128, n0 = by * 128;
  const char* Ag = (const char*)A + (size_t)m0 * kb;
  const char* Bg = (const char*)Bt + (size_t)n0 * kb;
  f32x4 acc[4][2] = {};
  stage_half(Ag, kb, 0, smem, tid);
  stage_half(Bg, kb, 0, smem + 49152, tid);
  stage_half(Ag, kb, 1, smem + 16384, tid);
  stage_half(Bg, kb, 1, smem + 49152 + 16384, tid);
  asm volatile("s_waitcnt vmcnt(4)" ::: "memory");
  BAR();
#pragma unroll
  for (int t = 0; t < 16; ++t) {
    const char* At = smem + (t % 3) * 16384;
    const char* Bb = smem + 49152 + (t % 3) * 16384;
    f16x8 bf[2][2], af[4][2];
#pragma unroll
    for (int nt = 0; nt < 2; ++nt) {
      bf[nt][0] = ldsfrag(Bb, wn + nt * 16 + lr, kg);
      bf[nt][1] = ldsfrag(Bb, wn + nt * 16 + lr, 4 + kg);
    }
#pragma unroll
    for (int m = 0; m < 4; ++m) {
      af[m][0] = ldsfrag(At, wm + m * 16 + lr, kg);
      af[m][1] = ldsfrag(At, wm + m * 16 + lr, 4 + kg);
    }
    if (t < 14) {
      stage_half(Ag, kb, t + 2, smem + ((t + 2) % 3) * 16384, tid);
      stage_half(Bg, kb, t + 2, smem + 49152 + ((t + 2) % 3) * 16384, tid);
    }
    BAR();
    __builtin_amdgcn_s_setprio(1);
#pragma unroll
    for (int m = 0; m < 4; ++m)
#pragma unroll
      for (int nt = 0; nt < 2; ++nt) {
        acc[m][nt] = mfma16(af[m][0], bf[nt][0], acc[m][nt]);
        acc[m][nt] = mfma16(af[m][1], bf[nt][1], acc[m][nt]);
      }
    __builtin_amdgcn_s_setprio(0);
    if (t < 14)
      asm volatile("s_waitcnt vmcnt(4)" ::: "memory");
    else if (t == 14)
      asm volatile("s_waitcnt vmcnt(0)" ::: "memory");
    BAR();
  }
#pragma unroll
  for (int nt = 0; nt < 2; ++nt) {
    const int col = n0 + wn + nt * 16 + lr;
    const float bv = bias[col];
#pragma unroll
    for (int mt = 0; mt < 4; ++mt) {
      const int row0 = m0 + wm + mt * 16 + kg * 4;
#pragma unroll
      for (int rr = 0; rr < 4; ++rr)
        C[(size_t)(row0 + rr) * 1024 + col] = acc[mt][nt][rr] + bv;
    }
  }
}

// ---------------- fused windowed attention, 192-window ----------------
__global__ __launch_bounds__(256) void attn_kernel(
    const _Float16* __restrict__ qkvh, const unsigned* __restrict__ masks,
    const int* __restrict__ sorted_idx, _Float16* __restrict__ attn_h) {
  __shared__ __align__(128) char sK[24576];  // K [192][128B]; later P [64][384B]
  __shared__ __align__(128) char sV[24576];  // V^T [64][384B] (swizzled)
  const int flat = (blockIdx.x & 7) * 128 + (blockIdx.x >> 3);
  const int b = flat & 63, h = flat >> 6;
  const int tid = threadIdx.x, lane = tid & 63, wid = tid >> 6;
  const int W0 = min(max(64 * b - 64, 0), NSEQ - 192);
  const int lrow16 = lane & 15, kgrp = lane >> 4;
  int ridx[6];
#pragma unroll
  for (int c = 0; c < 6; ++c)
    ridx[c] = sorted_idx[W0 + c * 32 + wid * 8 + (lane >> 3)];
#pragma unroll
  for (int c = 0; c < 6; ++c) {
    const int o = c * 4096 + wid * 1024 + lane * 16;
    const int row = o >> 7;
    const int inrow = (o & 127) ^ ((row & 7) << 4);
    glds16((const char*)qkvh + (size_t)ridx[c] * 6144 + 2048 + h * 128 + inrow,
           sK + o);
  }
  f16x8 vreg[6];
#pragma unroll
  for (int c = 0; c < 6; ++c) {
    const int o = c * 4096 + wid * 1024 + lane * 16;
    vreg[c] = *(const f16x8*)((const char*)qkvh + (size_t)ridx[c] * 6144 +
                              4096 + h * 128 + (o & 127));
  }
  const int p_base = b * 64 + wid * 16;
  const int orig_q = sorted_idx[p_base + lrow16];
  const char* qp = (const char*)qkvh + (size_t)orig_q * 6144 + h * 128 + kgrp * 16;
  const f16x8 aq0 = *(const f16x8*)qp;
  const f16x8 aq1 = *(const f16x8*)(qp + 64);
  unsigned mb[4];
#pragma unroll
  for (int r = 0; r < 4; ++r) {
    const int p = p_base + kgrp * 4 + r;
    const uint4 wa = *(const uint4*)&masks[p * 8];
    const uint2 wb2 = *(const uint2*)&masks[p * 8 + 4];
    const unsigned wsv6[6] = {wa.x, wa.y, wa.z, wa.w, wb2.x, wb2.y};
    unsigned bits = 0;
#pragma unroll
    for (int n = 0; n < 12; ++n)
      bits |= ((wsv6[n >> 1] >> (((n & 1) << 4) + lrow16)) & 1u) << n;
    mb[r] = bits;
  }
  const int lrot = lane & 7;
#pragma unroll
  for (int c = 0; c < 6; ++c) {
    const int o = c * 4096 + wid * 1024 + lane * 16;
    const int k = o >> 7;
    const int d0 = (o & 127) >> 1;
#pragma unroll
    for (int ee = 0; ee < 8; ++ee) {
      const int e = (ee + lrot) & 7;
      const int d = d0 + e;
      *(_Float16*)(sV + d * 384 + ((2 * k) ^ ((d & 7) << 4))) = vreg[c][e];
    }
  }
  __syncthreads();
  float sv[12][4];
#pragma unroll
  for (int n = 0; n < 12; ++n) {
    const int j = n * 16 + lrow16;
    const int sw = (j & 7) << 4;
    const char* kr = sK + j * 128;
    const f16x8 b0 = *(const f16x8*)(kr + ((kgrp * 16) ^ sw));
    const f16x8 b1 = *(const f16x8*)(kr + ((64 + kgrp * 16) ^ sw));
    f32x4 a = {};
    a = mfma16(aq0, b0, a);
    a = mfma16(aq1, b1, a);
#pragma unroll
    for (int r = 0; r < 4; ++r)
      sv[n][r] = ((mb[r] >> n) & 1u) ? a[r] * 0.125f : -1e30f;
  }
#pragma unroll
  for (int r = 0; r < 4; ++r) {
    float m = sv[0][r];
#pragma unroll
    for (int n = 1; n < 12; ++n) m = fmaxf(m, sv[n][r]);
    m = fmaxf(m, __shfl_xor(m, 1));
    m = fmaxf(m, __shfl_xor(m, 2));
    m = fmaxf(m, __shfl_xor(m, 4));
    m = fmaxf(m, __shfl_xor(m, 8));
    float s = 0.f;
#pragma unroll
    for (int n = 0; n < 12; ++n) {
      const float e = __expf(sv[n][r] - m);
      sv[n][r] = e;
      s += e;
    }
    s += __shfl_xor(s, 1);
    s += __shfl_xor(s, 2);
    s += __shfl_xor(s, 4);
    s += __shfl_xor(s, 8);
    const float rinv = 1.f / s;
#pragma unroll
    for (int n = 0; n < 12; ++n) sv[n][r] *= rinv;
  }
  __syncthreads();
#pragma unroll
  for (int n = 0; n < 12; ++n) {
#pragma unroll
    for (int r = 0; r < 4; ++r) {
      const int lrw = wid * 16 + kgrp * 4 + r;
      const int cb = (n * 16 + lrow16) * 2;
      *(_Float16*)(sK + lrw * 384 + (cb ^ ((lrw & 7) << 4))) = (_Float16)sv[n][r];
    }
  }
  __syncthreads();
  f32x4 oacc[4] = {};
  const int arow = wid * 16 + lrow16;
  const int swa = (arow & 7) << 4;
#pragma unroll
  for (int kt = 0; kt < 6; ++kt) {
    const int kbo = kt * 64 + kgrp * 16;
    const f16x8 pa = *(const f16x8*)(sK + arow * 384 + (kbo ^ swa));
#pragma unroll
    for (int nt = 0; nt < 4; ++nt) {
      const int d = nt * 16 + lrow16;
      const f16x8 vb = *(const f16x8*)(sV + d * 384 + (kbo ^ ((d & 7) << 4)));
      oacc[nt] = mfma16(pa, vb, oacc[nt]);
    }
  }
#pragma unroll
  for (int r = 0; r < 4; ++r) {
    const int p = p_base + kgrp * 4 + r;
    const int orig = sorted_idx[p];
    _Float16* op = attn_h + (size_t)orig * DIMM + h * 64;
#pragma unroll
    for (int nt = 0; nt < 4; ++nt)
      op[nt * 16 + lrow16] = (_Float16)oacc[nt][r];
  }
}

// ---------------- launch ----------------
extern "C" void kernel_launch(void* const* d_in, const int* in_sizes, int n_in,
                              void* d_out, int out_size, void* d_ws, size_t ws_size,
                              hipStream_t stream) {
  const float* x = (const float*)d_in[0];
  const float* cc = (const float*)d_in[1];
  const float* Wqkv = (const float*)d_in[2];
  const float* bqkv = (const float*)d_in[3];
  const float* Wout = (const float*)d_in[4];
  const float* bout = (const float*)d_in[5];
  char* ws = (char*)d_ws;

  _Float16* xh = (_Float16*)(ws + 0);                 //  8 MB
  _Float16* wqkvt = (_Float16*)(ws + 8388608);        //  6 MB
  _Float16* woutt = (_Float16*)(ws + 14680064);       //  2 MB
  _Float16* qkvh = (_Float16*)(ws + 16777216);        // 24 MB
  _Float16* atnh = (_Float16*)(ws + 41943040);        //  8 MB
  int* sidx = (int*)(ws + 50331648);                  // 16 KB
  float* csort = (float*)(ws + 50348032);             // 16 KB
  unsigned* msk = (unsigned*)(ws + 50364416);         // 128 KB

  hipFuncSetAttribute((const void*)qkv_gemm192_kernel,
                      hipFuncAttributeMaxDynamicSharedMemorySize, 114688);
  hipFuncSetAttribute((const void*)out_gemm128_kernel,
                      hipFuncAttributeMaxDynamicSharedMemorySize, 98304);

  prep_kernel<<<3200, 256, 0, stream>>>(x, xh, Wqkv, wqkvt, Wout, woutt, cc,
                                        sidx, csort);
  mask_kernel<<<1024, 256, 0, stream>>>(csort, sidx, msk);
  qkv_gemm192_kernel<<<256, 512, 114688, stream>>>(xh, wqkvt, bqkv, qkvh);
  attn_kernel<<<1024, 256, 0, stream>>>(qkvh, msk, sidx, atnh);
  out_gemm128_kernel<<<256, 512, 98304, stream>>>(atnh, woutt, bout,
                                                  (float*)d_out);
}